// Round 10
// baseline (311.578 us; speedup 1.0000x reference)
//
#include <hip/hip_runtime.h>
#include <float.h>
#include <stdint.h>

// Chamfer distance via MFMA (bf16 hi/lo compensated split), round 10.
// d[n][m] = ||t_m||^2 - 2 q_n . t_m  + ||q_n||^2 (folded into partial)
// One mfma_f32_32x32x16_bf16 computes a 32q x 32t tile of (tt - 2q.t):
//   A k-slots (query row, c = -2q): [chx chy chz clx cly clz chx chy |
//                                    chz 1 1 clx cly clz 0 0]
//   B k-slots (target col):         [bhx bhy bhz bhx bhy bhz blx bly |
//                                    blz tth ttl blx bly blz 0 0]
// B fragments prepacked by prep_kernel into ws (8 MB): H0 region = lanes
// 0-31 (k=0..7), H1 region = lanes 32-63 (k=8..15).
// R10 vs R9 (61us): all 4 waves of a block consume the SAME B-stream, so
// stage 256-target chunks in LDS (reg-staged, double-buffered, T14 split:
// load-early / ds_write-late) -> one L2 stream per block instead of four,
// and the per-wave L2->MFMA latency chain becomes a short ds_read.
// Loop math / A-pack / epilogue / TH=2 partials: R7/R9-proven, unchanged.

typedef short bf16x8 __attribute__((ext_vector_type(8)));
typedef float f32x16 __attribute__((ext_vector_type(16)));

#define BLK 256
#define ONE_BF 0x3F80u

__device__ __forceinline__ uint32_t bf16_rne(float f) {
    uint32_t u = __builtin_bit_cast(uint32_t, f);
    return (u + 0x7FFFu + ((u >> 16) & 1u)) >> 16;
}
__device__ __forceinline__ float bf16f(uint32_t h) {
    return __builtin_bit_cast(float, h << 16);
}

// ---- prep: 262144 points (arr0 = x, arr1 = recon), 16B H0 + 16B H1 each.
// Also zeroes the output accumulator (stream-ordered before reduce).
__global__ __launch_bounds__(BLK)
void prep_kernel(const float* __restrict__ x, const float* __restrict__ recon,
                 uint32_t* __restrict__ ws, float* __restrict__ out)
{
    int tid = blockIdx.x * BLK + threadIdx.x;     // 0..262143
    if (tid == 0) out[0] = 0.0f;
    int arr = tid >> 17;
    int p   = tid & 131071;
    const float* s = arr ? recon : x;
    float a = s[3 * p], b = s[3 * p + 1], c = s[3 * p + 2];
    uint32_t hx = bf16_rne(a), hy = bf16_rne(b), hz = bf16_rne(c);
    uint32_t lx = bf16_rne(a - bf16f(hx));
    uint32_t ly = bf16_rne(b - bf16f(hy));
    uint32_t lz = bf16_rne(c - bf16f(hz));
    float tt = a * a + b * b + c * c;
    uint32_t th = bf16_rne(tt);
    uint32_t tl = bf16_rne(tt - bf16f(th));
    uint4 H0 = make_uint4(hx | (hy << 16), hz | (hx << 16),
                          hy | (hz << 16), lx | (ly << 16));
    uint4 H1 = make_uint4(lz | (th << 16), tl | (lx << 16),
                          ly | (lz << 16), 0u);
    ((uint4*)ws)[tid]          = H0;
    ((uint4*)ws)[262144 + tid] = H1;
}

// ---- main (partial): 2048 blocks (XCD-swizzled), 4 waves.
// Block stages its 2048-target half in 8 chunks of 256 targets (8 KB),
// double-buffered in LDS; all 4 waves consume the same staged chunk.
__global__ __launch_bounds__(BLK)
void chamfer_mfma_p(const float* __restrict__ x, const float* __restrict__ recon,
                    const uint32_t* __restrict__ ws, float* __restrict__ ws2)
{
    // XCD-aware bijective swizzle (2048 % 8 == 0): CPX = 2048/8 = 256.
    int idx = blockIdx.x;
    int swz = (idx & 7) * 256 + (idx >> 3);
    int th  = swz & 1;
    int qb  = (swz >> 1) & 15;
    int b   = (swz >> 5) & 31;
    int dir = swz >> 10;

    const float* qsrc = dir ? recon : x;          // queries
    const int arrT = dir ? 0 : 1;                 // targets = other array

    const int tid  = threadIdx.x;
    const int wave = tid >> 6;
    const int lane = tid & 63;
    const int l31  = lane & 31;
    const int lh   = lane >> 5;

    // LDS: staging double-buffer (2 x 8 KB) unioned with epilogue matrix.
    __shared__ union U {
        uint4 stage[2][512];          // [buf][rec]: H0 recs 0..255, H1 256..511
        float lmin[256][17];
    } sh;

    // A fragments (R7-verbatim): row = l31 within each 32-row block.
    bf16x8 A0, A1;
    {
        int n0 = qb * 256 + wave * 64 + l31;
        #pragma unroll
        for (int rb = 0; rb < 2; ++rb) {
            const float* qp = qsrc + ((size_t)b * 4096 + n0 + rb * 32) * 3;
            float cx = -2.f * qp[0], cy = -2.f * qp[1], cz = -2.f * qp[2];
            uint32_t hx = bf16_rne(cx), hy = bf16_rne(cy), hz = bf16_rne(cz);
            uint32_t lx = bf16_rne(cx - bf16f(hx));
            uint32_t ly = bf16_rne(cy - bf16f(hy));
            uint32_t lz = bf16_rne(cz - bf16f(hz));
            uint32_t w0, w1, w2, w3;
            if (lh == 0) {
                w0 = hx | (hy << 16); w1 = hz | (lx << 16);
                w2 = ly | (lz << 16); w3 = hx | (hy << 16);
            } else {
                w0 = hz | (ONE_BF << 16); w1 = ONE_BF | (lx << 16);
                w2 = ly | (lz << 16);     w3 = 0u;
            }
            union { uint4 u; bf16x8 v; } cvt;
            cvt.u = make_uint4(w0, w1, w2, w3);
            if (rb == 0) A0 = cvt.v; else A1 = cvt.v;
        }
    }

    // Global B-record streams for this block's target half.
    const size_t rec_base = (size_t)arrT * 131072 + (size_t)b * 4096
                          + (size_t)th * 2048;
    const uint4* gH0 = (const uint4*)ws + rec_base;           // H0 region
    const uint4* gH1 = (const uint4*)ws + 262144 + rec_base;  // H1 region

    // Prologue: stage chunk 0.
    {
        uint4 r0 = gH0[tid];
        uint4 r1 = gH1[tid];
        sh.stage[0][tid]       = r0;
        sh.stage[0][256 + tid] = r1;
    }
    __syncthreads();

    f32x16 zc = {0,0,0,0,0,0,0,0,0,0,0,0,0,0,0,0};
    float rmn0[16], rmn1[16];
    #pragma unroll
    for (int j = 0; j < 16; ++j) { rmn0[j] = FLT_MAX; rmn1[j] = FLT_MAX; }

    #pragma unroll 2
    for (int c = 0; c < 8; ++c) {
        int buf = c & 1;
        // T14 split: issue next chunk's global loads BEFORE compute.
        uint4 r0, r1;
        if (c < 7) {
            r0 = gH0[(c + 1) * 256 + tid];
            r1 = gH1[(c + 1) * 256 + tid];
        }
        // Compute 4 pair-iters (256 targets) from staged chunk.
        const uint4* sb = &sh.stage[buf][lh * 256];
        #pragma unroll
        for (int i = 0; i < 4; ++i) {
            union BU { uint4 u; bf16x8 v; } B0, B1;
            B0.u = sb[(2 * i) * 32 + l31];
            B1.u = sb[(2 * i + 1) * 32 + l31];
            f32x16 d0 = __builtin_amdgcn_mfma_f32_32x32x16_bf16(A0, B0.v, zc, 0, 0, 0);
            f32x16 d1 = __builtin_amdgcn_mfma_f32_32x32x16_bf16(A0, B1.v, zc, 0, 0, 0);
            #pragma unroll
            for (int j = 0; j < 16; ++j)
                rmn0[j] = fminf(rmn0[j], fminf(d0[j], d1[j]));
            f32x16 e0 = __builtin_amdgcn_mfma_f32_32x32x16_bf16(A1, B0.v, zc, 0, 0, 0);
            f32x16 e1 = __builtin_amdgcn_mfma_f32_32x32x16_bf16(A1, B1.v, zc, 0, 0, 0);
            #pragma unroll
            for (int j = 0; j < 16; ++j)
                rmn1[j] = fminf(rmn1[j], fminf(e0[j], e1[j]));
        }
        // Write next chunk into the other buffer (safe: read in c+1, last
        // read of that buffer was c-1, all waves passed c-1's barrier).
        if (c < 7) {
            sh.stage[buf ^ 1][tid]       = r0;
            sh.stage[buf ^ 1][256 + tid] = r1;
        }
        __syncthreads();
    }

    // Epilogue (R9-proven): xor-16 col pre-fold, then LDS transpose at
    // half width (lmin[256][17]); final barrier of loop above guarantees
    // all staging reads are done before we overwrite the union.
    #pragma unroll
    for (int j = 0; j < 16; ++j) {
        int rl = (j & 3) + 8 * (j >> 2) + 4 * lh;  // verified 32x32 C/D row
        float a = fminf(rmn0[j], __shfl_xor(rmn0[j], 16, 64));
        float c = fminf(rmn1[j], __shfl_xor(rmn1[j], 16, 64));
        sh.lmin[wave * 64 + rl][l31 & 15]      = a;
        sh.lmin[wave * 64 + 32 + rl][l31 & 15] = c;
    }
    __syncthreads();

    float m = sh.lmin[tid][0];
    #pragma unroll
    for (int c = 1; c < 16; ++c) m = fminf(m, sh.lmin[tid][c]);

    // Per-query partial: min + ||q||^2, coalesced store.
    const float* qp = qsrc + ((size_t)b * 4096 + qb * 256 + tid) * 3;
    float v = m + qp[0] * qp[0] + qp[1] * qp[1] + qp[2] * qp[2];
    size_t base = (((size_t)th * 2 + dir) * 32 + b) * 4096
                + (size_t)qb * 256 + tid;
    ws2[base] = v;
}

// ---- reduce: min across 2 halves, global mean-sum, one atomic per block.
__global__ __launch_bounds__(BLK)
void chamfer_reduce(const float* __restrict__ ws2, float* __restrict__ out,
                    float scale)
{
    int q = blockIdx.x * BLK + threadIdx.x;       // 0..262143
    float v = fminf(ws2[q], ws2[262144 + q]);

    #pragma unroll
    for (int off = 32; off > 0; off >>= 1)
        v += __shfl_down(v, off, 64);

    __shared__ float red[4];
    int tid = threadIdx.x;
    if ((tid & 63) == 0) red[tid >> 6] = v;
    __syncthreads();
    if (tid == 0) {
        float s = red[0] + red[1] + red[2] + red[3];
        atomicAdd(out, s * scale);
    }
}

// ---- fallback (R7-verbatim, self-reducing): used only if ws too small.
__global__ __launch_bounds__(BLK, 3)
void chamfer_mfma_full(const float* __restrict__ x, const float* __restrict__ recon,
                       const uint32_t* __restrict__ ws, float* __restrict__ out,
                       float scale)
{
    int idx = blockIdx.x;
    int swz = (idx & 7) * 128 + (idx >> 3);
    int dir = swz >> 9;
    int b   = (swz >> 4) & 31;
    int qb  = swz & 15;
    const float* qsrc = dir ? recon : x;
    const int arrT = dir ? 0 : 1;
    const int tid  = threadIdx.x;
    const int wave = tid >> 6;
    const int lane = tid & 63;
    const int l31  = lane & 31;
    const int lh   = lane >> 5;
    bf16x8 A0, A1;
    {
        int n0 = qb * 256 + wave * 64 + l31;
        #pragma unroll
        for (int rb = 0; rb < 2; ++rb) {
            const float* qp = qsrc + ((size_t)b * 4096 + n0 + rb * 32) * 3;
            float cx = -2.f * qp[0], cy = -2.f * qp[1], cz = -2.f * qp[2];
            uint32_t hx = bf16_rne(cx), hy = bf16_rne(cy), hz = bf16_rne(cz);
            uint32_t lx = bf16_rne(cx - bf16f(hx));
            uint32_t ly = bf16_rne(cy - bf16f(hy));
            uint32_t lz = bf16_rne(cz - bf16f(hz));
            uint32_t w0, w1, w2, w3;
            if (lh == 0) { w0 = hx | (hy << 16); w1 = hz | (lx << 16);
                           w2 = ly | (lz << 16); w3 = hx | (hy << 16); }
            else         { w0 = hz | (ONE_BF << 16); w1 = ONE_BF | (lx << 16);
                           w2 = ly | (lz << 16);     w3 = 0u; }
            union { uint4 u; bf16x8 v; } cvt;
            cvt.u = make_uint4(w0, w1, w2, w3);
            if (rb == 0) A0 = cvt.v; else A1 = cvt.v;
        }
    }
    f32x16 zc = {0,0,0,0,0,0,0,0,0,0,0,0,0,0,0,0};
    float rmn0[16], rmn1[16];
    #pragma unroll
    for (int j = 0; j < 16; ++j) { rmn0[j] = FLT_MAX; rmn1[j] = FLT_MAX; }
    const uint4* rp = (const uint4*)ws
        + (size_t)lh * 262144 + (size_t)arrT * 131072 + (size_t)b * 4096 + l31;
    for (int it = 0; it < 64; ++it) {
        union BU { uint4 u; bf16x8 v; } B0, B1;
        B0.u = rp[0]; B1.u = rp[32]; rp += 64;
        f32x16 d0 = __builtin_amdgcn_mfma_f32_32x32x16_bf16(A0, B0.v, zc, 0, 0, 0);
        f32x16 d1 = __builtin_amdgcn_mfma_f32_32x32x16_bf16(A0, B1.v, zc, 0, 0, 0);
        #pragma unroll
        for (int j = 0; j < 16; ++j)
            rmn0[j] = fminf(rmn0[j], fminf(d0[j], d1[j]));
        f32x16 e0 = __builtin_amdgcn_mfma_f32_32x32x16_bf16(A1, B0.v, zc, 0, 0, 0);
        f32x16 e1 = __builtin_amdgcn_mfma_f32_32x32x16_bf16(A1, B1.v, zc, 0, 0, 0);
        #pragma unroll
        for (int j = 0; j < 16; ++j)
            rmn1[j] = fminf(rmn1[j], fminf(e0[j], e1[j]));
    }
    __shared__ float lmin[256][33];
    #pragma unroll
    for (int j = 0; j < 16; ++j) {
        int rl = (j & 3) + 8 * (j >> 2) + 4 * lh;
        lmin[wave * 64 + rl][l31]      = rmn0[j];
        lmin[wave * 64 + 32 + rl][l31] = rmn1[j];
    }
    __syncthreads();
    float m = lmin[tid][0];
    #pragma unroll
    for (int c = 1; c < 32; ++c) m = fminf(m, lmin[tid][c]);
    const float* qp = qsrc + ((size_t)b * 4096 + qb * 256 + tid) * 3;
    float v = m + qp[0] * qp[0] + qp[1] * qp[1] + qp[2] * qp[2];
    #pragma unroll
    for (int off = 32; off > 0; off >>= 1)
        v += __shfl_down(v, off, 64);
    __shared__ float red[4];
    if (lane == 0) red[wave] = v;
    __syncthreads();
    if (tid == 0)
        atomicAdd(out, (red[0] + red[1] + red[2] + red[3]) * scale);
}

extern "C" void kernel_launch(void* const* d_in, const int* in_sizes, int n_in,
                              void* d_out, int out_size, void* d_ws, size_t ws_size,
                              hipStream_t stream) {
    const float* x     = (const float*)d_in[0];
    const float* recon = (const float*)d_in[1];
    float* out = (float*)d_out;
    uint32_t* ws = (uint32_t*)d_ws;
    float* ws2 = (float*)((char*)d_ws + (size_t)8 * 1024 * 1024);

    const float scale = 1.0f / (32.0f * 4096.0f);

    prep_kernel<<<1024, BLK, 0, stream>>>(x, recon, ws, out);

    if (ws_size >= (size_t)10 * 1024 * 1024 + 512 * 1024) {
        chamfer_mfma_p<<<2048, BLK, 0, stream>>>(x, recon, ws, ws2);
        chamfer_reduce<<<1024, BLK, 0, stream>>>(ws2, out, scale);
    } else {
        chamfer_mfma_full<<<1024, BLK, 0, stream>>>(x, recon, ws, out, scale);
    }
}

// Round 11
// 124.188 us; speedup vs baseline: 2.5089x; 2.5089x over previous
//
#include <hip/hip_runtime.h>
#include <float.h>
#include <stdint.h>

// Chamfer distance via MFMA, round 11: SINGLE-PASS over unique tiles.
// d[b][n][m] computed ONCE; row-min (over m) -> x cost, col-min (over n)
// -> recon cost, both from the same MFMA tile. Halves MFMA + load work
// vs R4-R10 which ran both "directions" separately.
// One mfma_f32_32x32x16_bf16 computes a 32n x 32m tile of FULL distance:
//   A k-slots (query row, c = -2q): [chx chy chz clx cly clz chx chy |
//                                    chz 1 1 clx cly clz q2h q2l]
//   B k-slots (target col):         [bhx bhy bhz bhx bhy bhz blx bly |
//                                    blz tth ttl blx bly blz 1 1]
//   sum = (ch+cl).(bh+bl) + tt + q2 = ||q-t||^2  (err ~1e-4, kills in mean)
// B records prepacked (recon only, 4 MB). Row path: R7/R9-proven
// (rmn min3-fold, shfl16 prefold + lmin[256][17] transpose). Col path:
// per-lane fold16 of C-regs + shfl_xor(32) + LDS atomicMin(u32; values
// clamped >=0 so uint order == float order) + global atomicMin flush.
// No reg-staging, no double-buffer (R6/R10 spill lesson): direct L2 loads.

typedef short bf16x8 __attribute__((ext_vector_type(8)));
typedef float f32x16 __attribute__((ext_vector_type(16)));

#define BLK 256
#define ONE_BF 0x3F80u

__device__ __forceinline__ uint32_t bf16_rne(float f) {
    uint32_t u = __builtin_bit_cast(uint32_t, f);
    return (u + 0x7FFFu + ((u >> 16) & 1u)) >> 16;
}
__device__ __forceinline__ float bf16f(uint32_t h) {
    return __builtin_bit_cast(float, h << 16);
}
__device__ __forceinline__ float fold16(f32x16 v) {
    float a0 = fminf(v[0], v[1]),   a1 = fminf(v[2], v[3]);
    float a2 = fminf(v[4], v[5]),   a3 = fminf(v[6], v[7]);
    float a4 = fminf(v[8], v[9]),   a5 = fminf(v[10], v[11]);
    float a6 = fminf(v[12], v[13]), a7 = fminf(v[14], v[15]);
    a0 = fminf(a0, a1); a2 = fminf(a2, a3);
    a4 = fminf(a4, a5); a6 = fminf(a6, a7);
    return fminf(fminf(a0, a2), fminf(a4, a6));
}

// ---- prep: 131072 recon points -> B records (16B H0 + 16B H1 each);
// init gcol to +inf bits; zero out.  512 blocks x 256.
__global__ __launch_bounds__(BLK)
void prep_kernel(const float* __restrict__ recon,
                 uint32_t* __restrict__ wrec, uint32_t* __restrict__ gcol,
                 float* __restrict__ out)
{
    int tid = blockIdx.x * BLK + threadIdx.x;     // 0..131071
    if (tid == 0) out[0] = 0.0f;
    gcol[tid] = 0x7F800000u;                      // +inf
    float a = recon[3 * tid], b = recon[3 * tid + 1], c = recon[3 * tid + 2];
    uint32_t hx = bf16_rne(a), hy = bf16_rne(b), hz = bf16_rne(c);
    uint32_t lx = bf16_rne(a - bf16f(hx));
    uint32_t ly = bf16_rne(b - bf16f(hy));
    uint32_t lz = bf16_rne(c - bf16f(hz));
    float tt = a * a + b * b + c * c;
    uint32_t th = bf16_rne(tt);
    uint32_t tl = bf16_rne(tt - bf16f(th));
    uint4 H0 = make_uint4(hx | (hy << 16), hz | (hx << 16),
                          hy | (hz << 16), lx | (ly << 16));
    uint4 H1 = make_uint4(lz | (th << 16), tl | (lx << 16),
                          ly | (lz << 16), ONE_BF | (ONE_BF << 16));
    ((uint4*)wrec)[tid]          = H0;            // lanes 0-31 (k0-7)
    ((uint4*)wrec)[131072 + tid] = H1;            // lanes 32-63 (k8-15)
}

// ---- main: 512 blocks (XCD-swizzled; 32 b x 16 qb), 4 waves.
// Wave owns 64 x-queries (2 A-blocks) x all 4096 recon targets.
__global__ __launch_bounds__(BLK)
void chamfer_mfma(const float* __restrict__ x,
                  const uint32_t* __restrict__ wrec,
                  float* __restrict__ wrow, uint32_t* __restrict__ gcol)
{
    int idx = blockIdx.x;
    int swz = (idx & 7) * 64 + (idx >> 3);        // bijective, 512 % 8 == 0
    int qb  = swz & 15;
    int b   = swz >> 4;

    const int tid  = threadIdx.x;
    const int wave = tid >> 6;
    const int lane = tid & 63;
    const int l31  = lane & 31;
    const int lh   = lane >> 5;

    __shared__ unsigned colmin[4096];             // per-target block col-min
    __shared__ float lmin[256][17];               // row transpose (R9-proven)

    for (int k = tid; k < 4096; k += BLK) colmin[k] = 0x7F800000u;

    // A fragments: queries = x, with q2 hi/lo in k14/k15 (lh==1 w3).
    bf16x8 A0, A1;
    {
        int n0 = qb * 256 + wave * 64 + l31;
        #pragma unroll
        for (int rb = 0; rb < 2; ++rb) {
            const float* qp = x + ((size_t)b * 4096 + n0 + rb * 32) * 3;
            float ax = qp[0], ay = qp[1], az = qp[2];
            float q2 = ax * ax + ay * ay + az * az;
            float cx = -2.f * ax, cy = -2.f * ay, cz = -2.f * az;
            uint32_t hx = bf16_rne(cx), hy = bf16_rne(cy), hz = bf16_rne(cz);
            uint32_t lx = bf16_rne(cx - bf16f(hx));
            uint32_t ly = bf16_rne(cy - bf16f(hy));
            uint32_t lz = bf16_rne(cz - bf16f(hz));
            uint32_t qh = bf16_rne(q2);
            uint32_t ql = bf16_rne(q2 - bf16f(qh));
            uint32_t w0, w1, w2, w3;
            if (lh == 0) {
                w0 = hx | (hy << 16); w1 = hz | (lx << 16);
                w2 = ly | (lz << 16); w3 = hx | (hy << 16);
            } else {
                w0 = hz | (ONE_BF << 16); w1 = ONE_BF | (lx << 16);
                w2 = ly | (lz << 16);     w3 = qh | (ql << 16);
            }
            union { uint4 u; bf16x8 v; } cvt;
            cvt.u = make_uint4(w0, w1, w2, w3);
            if (rb == 0) A0 = cvt.v; else A1 = cvt.v;
        }
    }
    __syncthreads();                              // colmin init visible

    f32x16 zc = {0,0,0,0,0,0,0,0,0,0,0,0,0,0,0,0};
    float rmn0[16], rmn1[16];
    #pragma unroll
    for (int j = 0; j < 16; ++j) { rmn0[j] = FLT_MAX; rmn1[j] = FLT_MAX; }

    const uint4* rp = (const uint4*)wrec
        + (size_t)lh * 131072 + (size_t)b * 4096 + l31;

    for (int it = 0; it < 64; ++it) {             // 64 targets per iter
        union BU { uint4 u; bf16x8 v; } B0, B1;
        B0.u = rp[0];
        B1.u = rp[32];
        rp += 64;
        f32x16 d0 = __builtin_amdgcn_mfma_f32_32x32x16_bf16(A0, B0.v, zc, 0, 0, 0);
        f32x16 d1 = __builtin_amdgcn_mfma_f32_32x32x16_bf16(A0, B1.v, zc, 0, 0, 0);
        #pragma unroll
        for (int j = 0; j < 16; ++j)
            rmn0[j] = fminf(rmn0[j], fminf(d0[j], d1[j]));
        float f0 = fold16(d0);                    // col partial, rows of A0
        float f1 = fold16(d1);
        f32x16 e0 = __builtin_amdgcn_mfma_f32_32x32x16_bf16(A1, B0.v, zc, 0, 0, 0);
        f32x16 e1 = __builtin_amdgcn_mfma_f32_32x32x16_bf16(A1, B1.v, zc, 0, 0, 0);
        #pragma unroll
        for (int j = 0; j < 16; ++j)
            rmn1[j] = fminf(rmn1[j], fminf(e0[j], e1[j]));
        f0 = fminf(f0, fold16(e0));               // + rows of A1
        f1 = fminf(f1, fold16(e1));
        f0 = fminf(f0, __shfl_xor(f0, 32, 64));   // merge lane halves
        f1 = fminf(f1, __shfl_xor(f1, 32, 64));
        f0 = fmaxf(f0, 0.0f);                     // >=0 so uint order = float
        f1 = fmaxf(f1, 0.0f);
        if (lh == 0) {
            int m = it * 64 + l31;
            atomicMin(&colmin[m],      __float_as_uint(f0));
            atomicMin(&colmin[m + 32], __float_as_uint(f1));
        }
    }

    // Row epilogue (R9-proven): shfl16 prefold + half-width LDS transpose.
    #pragma unroll
    for (int j = 0; j < 16; ++j) {
        int rl = (j & 3) + 8 * (j >> 2) + 4 * lh;  // verified 32x32 C/D row
        float a = fminf(rmn0[j], __shfl_xor(rmn0[j], 16, 64));
        float c = fminf(rmn1[j], __shfl_xor(rmn1[j], 16, 64));
        lmin[wave * 64 + rl][l31 & 15]      = a;
        lmin[wave * 64 + 32 + rl][l31 & 15] = c;
    }
    __syncthreads();                              // also drains colmin atomics

    float m = lmin[tid][0];
    #pragma unroll
    for (int c = 1; c < 16; ++c) m = fminf(m, lmin[tid][c]);
    wrow[(size_t)b * 4096 + qb * 256 + tid] = fmaxf(m, 0.0f);

    // Flush block col-mins to global (combined across 16 qb via atomicMin).
    uint32_t* g = gcol + (size_t)b * 4096;
    #pragma unroll
    for (int k = 0; k < 16; ++k)
        atomicMin(&g[k * 256 + tid], colmin[k * 256 + tid]);
}

// ---- reduce: sum row costs + col costs, one atomic per block.
__global__ __launch_bounds__(BLK)
void chamfer_reduce(const float* __restrict__ wrow,
                    const uint32_t* __restrict__ gcol,
                    float* __restrict__ out, float scale)
{
    int q = blockIdx.x * BLK + threadIdx.x;       // 0..131071
    float v = wrow[q] + __uint_as_float(gcol[q]);

    #pragma unroll
    for (int off = 32; off > 0; off >>= 1)
        v += __shfl_down(v, off, 64);

    __shared__ float red[4];
    int tid = threadIdx.x;
    if ((tid & 63) == 0) red[tid >> 6] = v;
    __syncthreads();
    if (tid == 0) {
        float s = red[0] + red[1] + red[2] + red[3];
        atomicAdd(out, s * scale);
    }
}

extern "C" void kernel_launch(void* const* d_in, const int* in_sizes, int n_in,
                              void* d_out, int out_size, void* d_ws, size_t ws_size,
                              hipStream_t stream) {
    const float* x     = (const float*)d_in[0];
    const float* recon = (const float*)d_in[1];
    float* out = (float*)d_out;

    // ws layout: [0,4MB) B records | [4MB,4.5MB) wrow | [4.5MB,5MB) gcol
    uint32_t* wrec = (uint32_t*)d_ws;
    float*    wrow = (float*)((char*)d_ws + (size_t)4 * 1024 * 1024);
    uint32_t* gcol = (uint32_t*)((char*)d_ws + (size_t)4608 * 1024);

    const float scale = 1.0f / (32.0f * 4096.0f);

    prep_kernel<<<512, BLK, 0, stream>>>(recon, wrec, gcol, out);
    chamfer_mfma<<<512, BLK, 0, stream>>>(x, wrec, wrow, gcol);
    chamfer_reduce<<<512, BLK, 0, stream>>>(wrow, gcol, out, scale);
}